// Round 1
// baseline (1060.049 us; speedup 1.0000x reference)
//
#include <hip/hip_runtime.h>
#include <hip/hip_bf16.h>
#include <math.h>

#define B_   64
#define N_   2048
#define E_   32768
#define K_   1024
#define F_   128
#define C_   384
#define NB_  (B_ * N_)

__device__ __forceinline__ float bf2f(unsigned int u) {
  return __uint_as_float(u << 16);   // uses low 16 bits
}
__device__ __forceinline__ unsigned int f2bf(float f) {
  unsigned int x = __float_as_uint(f);
  return (x + 0x7fffu + ((x >> 16) & 1u)) >> 16;   // RNE
}

// ---------------- degree count ----------------
__global__ __launch_bounds__(256) void k_degcnt(const int* __restrict__ src,
                                                const int* __restrict__ dst,
                                                int* __restrict__ deg_out,
                                                int* __restrict__ deg_in) {
  int tid = blockIdx.x * 256 + threadIdx.x;     // B*E threads
  int b = tid >> 15;                            // E = 1<<15
  int e = tid & (E_ - 1);
  int s = src[b * E_ + e], d = dst[b * E_ + e];
  atomicAdd(&deg_out[b * N_ + s], 1);
  atomicAdd(&deg_in [b * N_ + d], 1);
}

// ---------------- norms ----------------
__global__ __launch_bounds__(256) void k_norms(const int* __restrict__ deg_out,
                                               const int* __restrict__ deg_in,
                                               float* __restrict__ norm_s,
                                               float* __restrict__ norm_d) {
  int i = blockIdx.x * 256 + threadIdx.x;       // NB_ threads
  int dv = deg_out[i], di = deg_in[i];
  norm_s[i] = dv > 0 ? rsqrtf((float)dv) : 0.f;
  norm_d[i] = di > 0 ? rsqrtf((float)di) : 0.f;
}

// ---------------- per-graph exclusive scan of deg_in -> row_ptr ----------------
__global__ __launch_bounds__(512) void k_scan(const int* __restrict__ deg_in,
                                              int* __restrict__ row_ptr) {
  __shared__ int part[512];
  int b = blockIdx.x, t = threadIdx.x;
  int v[4], s = 0;
  for (int i = 0; i < 4; i++) { v[i] = deg_in[b * N_ + t * 4 + i]; s += v[i]; }
  part[t] = s;
  __syncthreads();
  for (int off = 1; off < 512; off <<= 1) {
    int x = (t >= off) ? part[t - off] : 0;
    __syncthreads();
    part[t] += x;
    __syncthreads();
  }
  int run = part[t] - s;                        // exclusive base
  for (int i = 0; i < 4; i++) { row_ptr[b * (N_ + 1) + t * 4 + i] = run; run += v[i]; }
  if (t == 511) row_ptr[b * (N_ + 1) + N_] = run;
}

// ---------------- CSR fill (edges sorted by dst) ----------------
__global__ __launch_bounds__(256) void k_fill(const int* __restrict__ src,
                                              const int* __restrict__ dst,
                                              const int* __restrict__ row_ptr,
                                              int* __restrict__ cnt,
                                              int* __restrict__ csr) {
  int tid = blockIdx.x * 256 + threadIdx.x;
  int b = tid >> 15;
  int e = tid & (E_ - 1);
  int s = src[b * E_ + e], d = dst[b * E_ + e];
  int pos = row_ptr[b * (N_ + 1) + d] + atomicAdd(&cnt[b * N_ + d], 1);
  csr[b * E_ + pos] = s;
}

// ---------------- aggregate: agg[n][:] = norm_d[n] * sum_{e in in(n)} h[src]*norm_s[src] ----------------
template <bool BF>
__global__ __launch_bounds__(256) void k_agg(const void* __restrict__ hin_,
                                             int stride, int off,
                                             const int* __restrict__ row_ptr,
                                             const int* __restrict__ csr,
                                             const float* __restrict__ norm_s,
                                             const float* __restrict__ norm_d,
                                             unsigned short* __restrict__ agg) {
  int t = threadIdx.x;
  int nl = t >> 5, f4 = t & 31;                  // 8 nodes/block, 32 float4-groups
  int node = blockIdx.x * 8 + nl;
  int b = node >> 11, n = node & (N_ - 1);
  int r0 = row_ptr[b * (N_ + 1) + n], r1 = row_ptr[b * (N_ + 1) + n + 1];
  const int* cs = csr + b * E_;
  float a0 = 0.f, a1 = 0.f, a2 = 0.f, a3 = 0.f;
  for (int e = r0; e < r1; ++e) {
    int s = cs[e];
    float w = norm_s[b * N_ + s];
    if (BF) {
      const unsigned short* p = (const unsigned short*)hin_ + (size_t)(b * N_ + s) * stride + off + f4 * 4;
      uint2 u = *(const uint2*)p;
      a0 += w * bf2f(u.x); a1 += w * bf2f(u.x >> 16);
      a2 += w * bf2f(u.y); a3 += w * bf2f(u.y >> 16);
    } else {
      const float4 v = *(const float4*)((const float*)hin_ + (size_t)(b * N_ + s) * stride + f4 * 4);
      a0 += w * v.x; a1 += w * v.y; a2 += w * v.z; a3 += w * v.w;
    }
  }
  float wd = norm_d[node];
  a0 *= wd; a1 *= wd; a2 *= wd; a3 *= wd;
  uint2 o;
  o.x = f2bf(a0) | (f2bf(a1) << 16);
  o.y = f2bf(a2) | (f2bf(a3) << 16);
  *(uint2*)(agg + (size_t)node * F_ + f4 * 4) = o;
}

// ---------------- GEMM: cr[:, off:off+128] = agg(bf16) @ W(f32) + bias, out bf16 ----------------
__global__ __launch_bounds__(256) void k_gemm(const unsigned short* __restrict__ agg,
                                              const float* __restrict__ W,
                                              const float* __restrict__ bias,
                                              unsigned short* __restrict__ cr,
                                              int out_off) {
  __shared__ float As[64][129];
  __shared__ float Wc[32][128];
  int t = threadIdx.x;
  int row0 = blockIdx.x * 64;
  // stage A tile (64 x 128 bf16)
  for (int j = 0; j < 4; j++) {
    int idx = t * 32 + j * 8;
    int r = idx >> 7, k = idx & 127;
    uint4 u = *(const uint4*)(agg + (size_t)(row0 + r) * F_ + k);
    As[r][k + 0] = bf2f(u.x); As[r][k + 1] = bf2f(u.x >> 16);
    As[r][k + 2] = bf2f(u.y); As[r][k + 3] = bf2f(u.y >> 16);
    As[r][k + 4] = bf2f(u.z); As[r][k + 5] = bf2f(u.z >> 16);
    As[r][k + 6] = bf2f(u.w); As[r][k + 7] = bf2f(u.w >> 16);
  }
  float acc[4][8];
  for (int i = 0; i < 4; i++) for (int j = 0; j < 8; j++) acc[i][j] = 0.f;
  int tr = t >> 4, tc = t & 15;
  for (int k0 = 0; k0 < 128; k0 += 32) {
    __syncthreads();
    for (int j = 0; j < 4; j++) {
      int f4 = t + j * 256;                     // 0..1023
      int r = f4 >> 5, c4 = f4 & 31;
      *(float4*)&Wc[r][c4 * 4] = *(const float4*)(W + (size_t)(k0 + r) * F_ + c4 * 4);
    }
    __syncthreads();
    for (int k = 0; k < 32; k++) {
      float a0 = As[tr * 4 + 0][k0 + k];
      float a1 = As[tr * 4 + 1][k0 + k];
      float a2 = As[tr * 4 + 2][k0 + k];
      float a3 = As[tr * 4 + 3][k0 + k];
      const float4* wr = (const float4*)&Wc[k][0];
      float4 wa = wr[tc * 2], wb = wr[tc * 2 + 1];
      acc[0][0] += a0 * wa.x; acc[0][1] += a0 * wa.y; acc[0][2] += a0 * wa.z; acc[0][3] += a0 * wa.w;
      acc[0][4] += a0 * wb.x; acc[0][5] += a0 * wb.y; acc[0][6] += a0 * wb.z; acc[0][7] += a0 * wb.w;
      acc[1][0] += a1 * wa.x; acc[1][1] += a1 * wa.y; acc[1][2] += a1 * wa.z; acc[1][3] += a1 * wa.w;
      acc[1][4] += a1 * wb.x; acc[1][5] += a1 * wb.y; acc[1][6] += a1 * wb.z; acc[1][7] += a1 * wb.w;
      acc[2][0] += a2 * wa.x; acc[2][1] += a2 * wa.y; acc[2][2] += a2 * wa.z; acc[2][3] += a2 * wa.w;
      acc[2][4] += a2 * wb.x; acc[2][5] += a2 * wb.y; acc[2][6] += a2 * wb.z; acc[2][7] += a2 * wb.w;
      acc[3][0] += a3 * wa.x; acc[3][1] += a3 * wa.y; acc[3][2] += a3 * wa.z; acc[3][3] += a3 * wa.w;
      acc[3][4] += a3 * wb.x; acc[3][5] += a3 * wb.y; acc[3][6] += a3 * wb.z; acc[3][7] += a3 * wb.w;
    }
  }
  float bv[8];
  for (int j = 0; j < 8; j++) bv[j] = bias[tc * 8 + j];
  for (int i = 0; i < 4; i++) {
    int r = row0 + tr * 4 + i;
    float v0 = acc[i][0] + bv[0], v1 = acc[i][1] + bv[1], v2 = acc[i][2] + bv[2], v3 = acc[i][3] + bv[3];
    float v4 = acc[i][4] + bv[4], v5 = acc[i][5] + bv[5], v6 = acc[i][6] + bv[6], v7 = acc[i][7] + bv[7];
    uint4 pk;
    pk.x = f2bf(v0) | (f2bf(v1) << 16);
    pk.y = f2bf(v2) | (f2bf(v3) << 16);
    pk.z = f2bf(v4) | (f2bf(v5) << 16);
    pk.w = f2bf(v6) | (f2bf(v7) << 16);
    *(uint4*)(cr + (size_t)r * C_ + out_off + tc * 8) = pk;
  }
}

// ---------------- score stage 1: y[n] = (cr[n] . Ws) * norm_s[n] ----------------
__global__ __launch_bounds__(256) void k_score_y(const unsigned short* __restrict__ cr,
                                                 const float* __restrict__ Wsc,
                                                 const float* __restrict__ norm_s,
                                                 float* __restrict__ y) {
  int node = blockIdx.x * 4 + (threadIdx.x >> 6);
  int lane = threadIdx.x & 63;
  const unsigned short* row = cr + (size_t)node * C_;
  float acc = 0.f;
  for (int f = lane; f < C_; f += 64) acc += bf2f(row[f]) * Wsc[f];
  for (int off = 32; off > 0; off >>= 1) acc += __shfl_xor(acc, off);
  if (lane == 0) y[node] = acc * norm_s[node];
}

// ---------------- score stage 2: score[n] = norm_d[n] * sum_in y[src] + bs ----------------
__global__ __launch_bounds__(256) void k_score_agg(const float* __restrict__ y,
                                                   const int* __restrict__ row_ptr,
                                                   const int* __restrict__ csr,
                                                   const float* __restrict__ norm_d,
                                                   const float* __restrict__ bs,
                                                   float* __restrict__ score) {
  int node = blockIdx.x * 256 + threadIdx.x;
  int b = node >> 11, n = node & (N_ - 1);
  int r0 = row_ptr[b * (N_ + 1) + n], r1 = row_ptr[b * (N_ + 1) + n + 1];
  const int* cs = csr + b * E_;
  float a = 0.f;
  for (int e = r0; e < r1; ++e) a += y[b * N_ + cs[e]];
  score[node] = norm_d[node] * a + bs[0];
}

// ---------------- top-k selection per graph (K=1024 of 2048) ----------------
__global__ __launch_bounds__(256) void k_topk(const float* __restrict__ score,
                                              float* __restrict__ selw,
                                              int* __restrict__ flags) {
  __shared__ unsigned int keys[N_];
  __shared__ int red[256];
  int b = blockIdx.x, t = threadIdx.x;
  for (int i = t; i < N_; i += 256) {
    unsigned u = __float_as_uint(score[b * N_ + i]);
    keys[i] = (u & 0x80000000u) ? ~u : (u | 0x80000000u);
  }
  __syncthreads();
  unsigned prefix = 0;
  for (int bit = 31; bit >= 0; bit--) {
    unsigned cand = prefix | (1u << bit);
    int c = 0;
    for (int i = t; i < N_; i += 256) c += ((keys[i] >> bit) >= (cand >> bit));
    red[t] = c;
    __syncthreads();
    for (int off = 128; off > 0; off >>= 1) { if (t < off) red[t] += red[t + off]; __syncthreads(); }
    if (red[0] >= K_) prefix = cand;
    __syncthreads();
  }
  unsigned T = prefix;
  // strictly-greater count
  int c = 0;
  for (int i = t; i < N_; i += 256) c += (keys[i] > T);
  red[t] = c;
  __syncthreads();
  for (int off = 128; off > 0; off >>= 1) { if (t < off) red[t] += red[t + off]; __syncthreads(); }
  int R = K_ - red[0];                          // ties to take, index order
  __syncthreads();
  // index-ordered tie ranking: thread owns contiguous elements [t*8, t*8+8)
  unsigned kk[8]; int myt = 0;
  for (int j = 0; j < 8; j++) { kk[j] = keys[t * 8 + j]; myt += (kk[j] == T); }
  red[t] = myt;
  __syncthreads();
  for (int off = 1; off < 256; off <<= 1) {
    int x = (t >= off) ? red[t - off] : 0;
    __syncthreads();
    red[t] += x;
    __syncthreads();
  }
  int rank = red[t] - myt;
  for (int j = 0; j < 8; j++) {
    int i = t * 8 + j;
    bool tie = (kk[j] == T);
    bool sel = (kk[j] > T) || (tie && rank < R);
    if (tie) rank++;
    flags[b * N_ + i] = sel ? 1 : 0;
    selw[b * N_ + i] = sel ? tanhf(score[b * N_ + i]) : 0.f;
  }
}

// ---------------- readout partials: sum & max of selected tanh-weighted rows ----------------
__global__ __launch_bounds__(384) void k_readout_part(const unsigned short* __restrict__ cr,
                                                      const float* __restrict__ selw,
                                                      const int* __restrict__ flags,
                                                      float* __restrict__ psum,
                                                      float* __restrict__ pmax) {
  __shared__ int fl[128];
  __shared__ float wv[128];
  int b = blockIdx.x >> 4, ch = blockIdx.x & 15;
  int f = threadIdx.x;
  int n0 = ch * 128;
  if (f < 128) { fl[f] = flags[b * N_ + n0 + f]; wv[f] = selw[b * N_ + n0 + f]; }
  __syncthreads();
  float sum = 0.f, mx = -3.402823466e38f;
  const unsigned short* base = cr + ((size_t)b * N_ + n0) * C_ + f;
  for (int n = 0; n < 128; n++) {
    float v = bf2f(base[(size_t)n * C_]);
    if (fl[n]) { float x = v * wv[n]; sum += x; mx = fmaxf(mx, x); }
  }
  psum[((size_t)b * 16 + ch) * C_ + f] = sum;
  pmax[((size_t)b * 16 + ch) * C_ + f] = mx;
}

__global__ __launch_bounds__(384) void k_readout_red(const float* __restrict__ psum,
                                                     const float* __restrict__ pmax,
                                                     float* __restrict__ g) {
  int b = blockIdx.x, f = threadIdx.x;
  float s = 0.f, m = -3.402823466e38f;
  for (int ch = 0; ch < 16; ch++) {
    s += psum[((size_t)b * 16 + ch) * C_ + f];
    m = fmaxf(m, pmax[((size_t)b * 16 + ch) * C_ + f]);
  }
  g[b * 768 + f] = s * (1.f / K_);
  g[b * 768 + C_ + f] = m;
}

// ---------------- MLP layer 1: h1 = g @ w1 ----------------
__global__ __launch_bounds__(128) void k_mlp1(const float* __restrict__ g,
                                              const float* __restrict__ w1,
                                              float* __restrict__ h1) {
  __shared__ float gr[768];
  int b = blockIdx.x, t = threadIdx.x;
  for (int i = t; i < 768; i += 128) gr[i] = g[b * 768 + i];
  __syncthreads();
  float acc = 0.f;
  for (int k = 0; k < 768; k++) acc += gr[k] * w1[(size_t)k * 128 + t];
  h1[b * 128 + t] = acc;
}

// ---------------- BN + ReLU + mlp_w2 + log_softmax ----------------
__global__ __launch_bounds__(128) void k_mlp2(const float* __restrict__ h1,
                                              const float* __restrict__ bn_g,
                                              const float* __restrict__ bn_b,
                                              const float* __restrict__ w2,
                                              float* __restrict__ out) {
  __shared__ float hn[64][128];
  __shared__ float o[64][10];
  int t = threadIdx.x;   // 128
  float mean = 0.f;
  for (int r = 0; r < 64; r++) mean += h1[r * 128 + t];
  mean *= (1.f / 64.f);
  float var = 0.f;
  for (int r = 0; r < 64; r++) { float d = h1[r * 128 + t] - mean; var += d * d; }
  var *= (1.f / 64.f);
  float sc = bn_g[t] * rsqrtf(var + 1e-5f), sh = bn_b[t];
  for (int r = 0; r < 64; r++) {
    float v = (h1[r * 128 + t] - mean) * sc + sh;
    hn[r][t] = fmaxf(v, 0.f);
  }
  __syncthreads();
  for (int j = 0; j < 5; j++) {
    int idx = t + j * 128;           // 0..639
    int r = idx / 10, c = idx % 10;
    float a = 0.f;
    for (int k = 0; k < 128; k++) a += hn[r][k] * w2[k * 10 + c];
    o[r][c] = a;
  }
  __syncthreads();
  if (t < 64) {
    float mx = -3.402823466e38f;
    for (int c = 0; c < 10; c++) mx = fmaxf(mx, o[t][c]);
    float se = 0.f;
    for (int c = 0; c < 10; c++) se += expf(o[t][c] - mx);
    float l = logf(se);
    for (int c = 0; c < 10; c++) out[t * 10 + c] = o[t][c] - mx - l;
  }
}

extern "C" void kernel_launch(void* const* d_in, const int* in_sizes, int n_in,
                              void* d_out, int out_size, void* d_ws, size_t ws_size,
                              hipStream_t stream) {
  const float* feat = (const float*)d_in[0];
  const int* src = (const int*)d_in[1];
  const int* dst = (const int*)d_in[2];
  const float* W0 = (const float*)d_in[3];  const float* b0 = (const float*)d_in[4];
  const float* W1 = (const float*)d_in[5];  const float* b1 = (const float*)d_in[6];
  const float* W2 = (const float*)d_in[7];  const float* b2 = (const float*)d_in[8];
  const float* Ws = (const float*)d_in[9];  const float* bs = (const float*)d_in[10];
  const float* mw1 = (const float*)d_in[11];
  const float* bng = (const float*)d_in[12];
  const float* bnb = (const float*)d_in[13];
  const float* mw2 = (const float*)d_in[14];
  float* out = (float*)d_out;

  char* p = (char*)d_ws;
  auto alloc = [&](size_t bytes) -> void* {
    void* r = (void*)p;
    p += (bytes + 255) & ~(size_t)255;
    return r;
  };
  int* deg_out = (int*)alloc((size_t)NB_ * 4);
  int* deg_in  = (int*)alloc((size_t)NB_ * 4);
  int* cnt     = (int*)alloc((size_t)NB_ * 4);
  int* row_ptr = (int*)alloc((size_t)B_ * (N_ + 1) * 4);
  float* norm_s = (float*)alloc((size_t)NB_ * 4);
  float* norm_d = (float*)alloc((size_t)NB_ * 4);
  int* csr      = (int*)alloc((size_t)B_ * E_ * 4);
  unsigned short* cr  = (unsigned short*)alloc((size_t)NB_ * C_ * 2);
  unsigned short* agg = (unsigned short*)alloc((size_t)NB_ * F_ * 2);
  float* y     = (float*)alloc((size_t)NB_ * 4);
  float* score = (float*)alloc((size_t)NB_ * 4);
  float* selw  = (float*)alloc((size_t)NB_ * 4);
  int* flags   = (int*)alloc((size_t)NB_ * 4);
  float* psum  = (float*)alloc((size_t)B_ * 16 * C_ * 4);
  float* pmax  = (float*)alloc((size_t)B_ * 16 * C_ * 4);
  float* g     = (float*)alloc((size_t)B_ * 768 * 4);
  float* h1    = (float*)alloc((size_t)B_ * 128 * 4);

  // zero degree counters + fill counters (contiguous: deg_out, deg_in, cnt)
  hipMemsetAsync(deg_out, 0, (size_t)NB_ * 4 * 3, stream);

  k_degcnt<<<dim3(B_ * E_ / 256), dim3(256), 0, stream>>>(src, dst, deg_out, deg_in);
  k_norms<<<dim3(NB_ / 256), dim3(256), 0, stream>>>(deg_out, deg_in, norm_s, norm_d);
  k_scan<<<dim3(B_), dim3(512), 0, stream>>>(deg_in, row_ptr);
  k_fill<<<dim3(B_ * E_ / 256), dim3(256), 0, stream>>>(src, dst, row_ptr, cnt, csr);

  // layer 0: feat (f32, stride 128) -> cr[:, 0:128]
  k_agg<false><<<dim3(NB_ / 8), dim3(256), 0, stream>>>(feat, F_, 0, row_ptr, csr, norm_s, norm_d, agg);
  k_gemm<<<dim3(NB_ / 64), dim3(256), 0, stream>>>(agg, W0, b0, cr, 0);
  // layer 1: cr[:, 0:128] -> cr[:, 128:256]
  k_agg<true><<<dim3(NB_ / 8), dim3(256), 0, stream>>>(cr, C_, 0, row_ptr, csr, norm_s, norm_d, agg);
  k_gemm<<<dim3(NB_ / 64), dim3(256), 0, stream>>>(agg, W1, b1, cr, 128);
  // layer 2: cr[:, 128:256] -> cr[:, 256:384]
  k_agg<true><<<dim3(NB_ / 8), dim3(256), 0, stream>>>(cr, C_, 128, row_ptr, csr, norm_s, norm_d, agg);
  k_gemm<<<dim3(NB_ / 64), dim3(256), 0, stream>>>(agg, W2, b2, cr, 256);

  // SAGPool score
  k_score_y<<<dim3(NB_ / 4), dim3(256), 0, stream>>>(cr, Ws, norm_s, y);
  k_score_agg<<<dim3(NB_ / 256), dim3(256), 0, stream>>>(y, row_ptr, csr, norm_d, bs, score);
  k_topk<<<dim3(B_), dim3(256), 0, stream>>>(score, selw, flags);

  // readout
  k_readout_part<<<dim3(B_ * 16), dim3(384), 0, stream>>>(cr, selw, flags, psum, pmax);
  k_readout_red<<<dim3(B_), dim3(384), 0, stream>>>(psum, pmax, g);

  // MLP
  k_mlp1<<<dim3(B_), dim3(128), 0, stream>>>(g, mw1, h1);
  k_mlp2<<<dim3(1), dim3(128), 0, stream>>>(h1, bng, bnb, mw2, out);
}

// Round 3
// 817.652 us; speedup vs baseline: 1.2965x; 1.2965x over previous
//
#include <hip/hip_runtime.h>
#include <hip/hip_bf16.h>
#include <math.h>

#define B_   64
#define N_   2048
#define E_   32768
#define K_   1024
#define F_   128
#define C_   384
#define NB_  (B_ * N_)

typedef __bf16 bf16x8 __attribute__((ext_vector_type(8)));
typedef float  f32x4  __attribute__((ext_vector_type(4)));

__device__ __forceinline__ float bf2f(unsigned int u) {
  return __uint_as_float(u << 16);   // uses low 16 bits
}
__device__ __forceinline__ unsigned int f2bf(float f) {
  unsigned int x = __float_as_uint(f);
  return (x + 0x7fffu + ((x >> 16) & 1u)) >> 16;   // RNE
}

// ---------------- degree count ----------------
__global__ __launch_bounds__(256) void k_degcnt(const int* __restrict__ src,
                                                const int* __restrict__ dst,
                                                int* __restrict__ deg_out,
                                                int* __restrict__ deg_in) {
  int tid = blockIdx.x * 256 + threadIdx.x;     // B*E threads
  int b = tid >> 15;                            // E = 1<<15
  int e = tid & (E_ - 1);
  int s = src[b * E_ + e], d = dst[b * E_ + e];
  atomicAdd(&deg_out[b * N_ + s], 1);
  atomicAdd(&deg_in [b * N_ + d], 1);
}

// ---------------- norms ----------------
__global__ __launch_bounds__(256) void k_norms(const int* __restrict__ deg_out,
                                               const int* __restrict__ deg_in,
                                               float* __restrict__ norm_s,
                                               float* __restrict__ norm_d) {
  int i = blockIdx.x * 256 + threadIdx.x;       // NB_ threads
  int dv = deg_out[i], di = deg_in[i];
  norm_s[i] = dv > 0 ? rsqrtf((float)dv) : 0.f;
  norm_d[i] = di > 0 ? rsqrtf((float)di) : 0.f;
}

// ---------------- per-graph exclusive scan of deg_in -> row_ptr ----------------
__global__ __launch_bounds__(512) void k_scan(const int* __restrict__ deg_in,
                                              int* __restrict__ row_ptr) {
  __shared__ int part[512];
  int b = blockIdx.x, t = threadIdx.x;
  int v[4], s = 0;
  for (int i = 0; i < 4; i++) { v[i] = deg_in[b * N_ + t * 4 + i]; s += v[i]; }
  part[t] = s;
  __syncthreads();
  for (int off = 1; off < 512; off <<= 1) {
    int x = (t >= off) ? part[t - off] : 0;
    __syncthreads();
    part[t] += x;
    __syncthreads();
  }
  int run = part[t] - s;                        // exclusive base
  for (int i = 0; i < 4; i++) { row_ptr[b * (N_ + 1) + t * 4 + i] = run; run += v[i]; }
  if (t == 511) row_ptr[b * (N_ + 1) + N_] = run;
}

// ---------------- CSR fill (edges sorted by dst) ----------------
__global__ __launch_bounds__(256) void k_fill(const int* __restrict__ src,
                                              const int* __restrict__ dst,
                                              const int* __restrict__ row_ptr,
                                              int* __restrict__ cnt,
                                              int* __restrict__ csr) {
  int tid = blockIdx.x * 256 + threadIdx.x;
  int b = tid >> 15;
  int e = tid & (E_ - 1);
  int s = src[b * E_ + e], d = dst[b * E_ + e];
  int pos = row_ptr[b * (N_ + 1) + d] + atomicAdd(&cnt[b * N_ + d], 1);
  csr[b * E_ + pos] = s;
}

// ---------------- feat f32 -> bf16 ----------------
__global__ __launch_bounds__(256) void k_f2bf(const float* __restrict__ in,
                                              unsigned short* __restrict__ out) {
  int i = blockIdx.x * 256 + threadIdx.x;       // NB*128/8 threads, 8 elems each
  const float4* p = (const float4*)(in + (size_t)i * 8);
  float4 v0 = p[0], v1 = p[1];
  uint4 o;
  o.x = f2bf(v0.x) | (f2bf(v0.y) << 16);
  o.y = f2bf(v0.z) | (f2bf(v0.w) << 16);
  o.z = f2bf(v1.x) | (f2bf(v1.y) << 16);
  o.w = f2bf(v1.z) | (f2bf(v1.w) << 16);
  *(uint4*)(out + (size_t)i * 8) = o;
}

// ---------------- aggregate: agg[n][:] = norm_d[n] * sum_{e in in(n)} h[src]*norm_s[src] ----------------
template <bool BF>
__global__ __launch_bounds__(256) void k_agg(const void* __restrict__ hin_,
                                             int stride, int off,
                                             const int* __restrict__ row_ptr,
                                             const int* __restrict__ csr,
                                             const float* __restrict__ norm_s,
                                             const float* __restrict__ norm_d,
                                             unsigned short* __restrict__ agg) {
  int t = threadIdx.x;
  int nl = t >> 5, f4 = t & 31;                  // 8 nodes/block, 32 float4-groups
  int node = blockIdx.x * 8 + nl;
  int b = node >> 11, n = node & (N_ - 1);
  int r0 = row_ptr[b * (N_ + 1) + n], r1 = row_ptr[b * (N_ + 1) + n + 1];
  const int* cs = csr + b * E_;
  float a0 = 0.f, a1 = 0.f, a2 = 0.f, a3 = 0.f;
  for (int e = r0; e < r1; ++e) {
    int s = cs[e];
    float w = norm_s[b * N_ + s];
    if (BF) {
      const unsigned short* p = (const unsigned short*)hin_ + (size_t)(b * N_ + s) * stride + off + f4 * 4;
      uint2 u = *(const uint2*)p;
      a0 += w * bf2f(u.x); a1 += w * bf2f(u.x >> 16);
      a2 += w * bf2f(u.y); a3 += w * bf2f(u.y >> 16);
    } else {
      const float4 v = *(const float4*)((const float*)hin_ + (size_t)(b * N_ + s) * stride + f4 * 4);
      a0 += w * v.x; a1 += w * v.y; a2 += w * v.z; a3 += w * v.w;
    }
  }
  float wd = norm_d[node];
  a0 *= wd; a1 *= wd; a2 *= wd; a3 *= wd;
  uint2 o;
  o.x = f2bf(a0) | (f2bf(a1) << 16);
  o.y = f2bf(a2) | (f2bf(a3) << 16);
  *(uint2*)(agg + (size_t)node * F_ + f4 * 4) = o;
}

// ---------------- pack W (f32 [128k][128n]) into MFMA B-fragment layout, bf16 hi/lo ----------------
// fragment (kt, nt): lane holds 8 elems: k = kt*32 + (lane>>4)*8 + j, n = nt*16 + (lane&15)
// 32 fragments x 64 lanes = 2048 threads total.
__global__ __launch_bounds__(256) void k_packW(const float* __restrict__ W,
                                               unsigned short* __restrict__ wp_hi,
                                               unsigned short* __restrict__ wp_lo) {
  int tid = blockIdx.x * 256 + threadIdx.x;     // 2048 = 32 frags * 64 lanes
  int lane = tid & 63, frag = tid >> 6;         // frag = kt*8 + nt
  if (frag >= 32) return;
  int kt = frag >> 3, nt = frag & 7;
  int k0 = kt * 32 + (lane >> 4) * 8;
  int n = nt * 16 + (lane & 15);
  for (int j = 0; j < 8; j++) {
    float w = W[(size_t)(k0 + j) * 128 + n];
    unsigned int hi = f2bf(w);
    float whi = bf2f(hi);
    unsigned int lo = f2bf(w - whi);
    wp_hi[(size_t)tid * 8 + j] = (unsigned short)hi;
    wp_lo[(size_t)tid * 8 + j] = (unsigned short)lo;
  }
}

// ---------------- MFMA GEMM: cr[:, off:off+128] = agg(bf16) @ (Whi+Wlo) + bias ----------------
__global__ __launch_bounds__(256) void k_gemm_mfma(const unsigned short* __restrict__ agg,
                                                   const unsigned short* __restrict__ wp_hi,
                                                   const unsigned short* __restrict__ wp_lo,
                                                   const float* __restrict__ bias,
                                                   unsigned short* __restrict__ cr,
                                                   int out_off) {
  int t = threadIdx.x;
  int wave = t >> 6, lane = t & 63;
  int r0 = blockIdx.x * 128 + wave * 32;        // 32 rows per wave
  int arow = lane & 15, kg = lane >> 4;

  f32x4 acc[2][8];
#pragma unroll
  for (int i = 0; i < 2; i++)
#pragma unroll
    for (int j = 0; j < 8; j++) acc[i][j] = (f32x4){0.f, 0.f, 0.f, 0.f};

#pragma unroll
  for (int kt = 0; kt < 4; ++kt) {
    bf16x8 a0 = *(const bf16x8*)(agg + (size_t)(r0 + arow) * F_ + kt * 32 + kg * 8);
    bf16x8 a1 = *(const bf16x8*)(agg + (size_t)(r0 + 16 + arow) * F_ + kt * 32 + kg * 8);
    const unsigned short* bh = wp_hi + ((size_t)(kt * 8) * 64 + lane) * 8;
    const unsigned short* bl = wp_lo + ((size_t)(kt * 8) * 64 + lane) * 8;
#pragma unroll
    for (int nt = 0; nt < 8; ++nt) {
      bf16x8 bhv = *(const bf16x8*)(bh + (size_t)nt * 64 * 8);
      bf16x8 blv = *(const bf16x8*)(bl + (size_t)nt * 64 * 8);
      acc[0][nt] = __builtin_amdgcn_mfma_f32_16x16x32_bf16(a0, bhv, acc[0][nt], 0, 0, 0);
      acc[0][nt] = __builtin_amdgcn_mfma_f32_16x16x32_bf16(a0, blv, acc[0][nt], 0, 0, 0);
      acc[1][nt] = __builtin_amdgcn_mfma_f32_16x16x32_bf16(a1, bhv, acc[1][nt], 0, 0, 0);
      acc[1][nt] = __builtin_amdgcn_mfma_f32_16x16x32_bf16(a1, blv, acc[1][nt], 0, 0, 0);
    }
  }

  int colt = lane & 15, rbase = (lane >> 4) * 4;
#pragma unroll
  for (int nt = 0; nt < 8; ++nt) {
    float bv = bias[nt * 16 + colt];
#pragma unroll
    for (int rt = 0; rt < 2; ++rt) {
#pragma unroll
      for (int q = 0; q < 4; ++q) {
        int row = r0 + rt * 16 + rbase + q;
        float v = acc[rt][nt][q] + bv;
        cr[(size_t)row * C_ + out_off + nt * 16 + colt] = (unsigned short)f2bf(v);
      }
    }
  }
}

// ---------------- score stage 1: y[n] = (cr[n] . Ws) * norm_s[n] ----------------
__global__ __launch_bounds__(256) void k_score_y(const unsigned short* __restrict__ cr,
                                                 const float* __restrict__ Wsc,
                                                 const float* __restrict__ norm_s,
                                                 float* __restrict__ y) {
  int node = blockIdx.x * 4 + (threadIdx.x >> 6);
  int lane = threadIdx.x & 63;
  const unsigned short* row = cr + (size_t)node * C_;
  float acc = 0.f;
  for (int f = lane; f < C_; f += 64) acc += bf2f(row[f]) * Wsc[f];
  for (int off = 32; off > 0; off >>= 1) acc += __shfl_xor(acc, off);
  if (lane == 0) y[node] = acc * norm_s[node];
}

// ---------------- score stage 2: score[n] = norm_d[n] * sum_in y[src] + bs ----------------
__global__ __launch_bounds__(256) void k_score_agg(const float* __restrict__ y,
                                                   const int* __restrict__ row_ptr,
                                                   const int* __restrict__ csr,
                                                   const float* __restrict__ norm_d,
                                                   const float* __restrict__ bs,
                                                   float* __restrict__ score) {
  int node = blockIdx.x * 256 + threadIdx.x;
  int b = node >> 11, n = node & (N_ - 1);
  int r0 = row_ptr[b * (N_ + 1) + n], r1 = row_ptr[b * (N_ + 1) + n + 1];
  const int* cs = csr + b * E_;
  float a = 0.f;
  for (int e = r0; e < r1; ++e) a += y[b * N_ + cs[e]];
  score[node] = norm_d[node] * a + bs[0];
}

// ---------------- top-k selection per graph (K=1024 of 2048) ----------------
__global__ __launch_bounds__(256) void k_topk(const float* __restrict__ score,
                                              float* __restrict__ selw,
                                              int* __restrict__ flags) {
  __shared__ unsigned int keys[N_];
  __shared__ int red[256];
  int b = blockIdx.x, t = threadIdx.x;
  for (int i = t; i < N_; i += 256) {
    unsigned u = __float_as_uint(score[b * N_ + i]);
    keys[i] = (u & 0x80000000u) ? ~u : (u | 0x80000000u);
  }
  __syncthreads();
  unsigned prefix = 0;
  for (int bit = 31; bit >= 0; bit--) {
    unsigned cand = prefix | (1u << bit);
    int c = 0;
    for (int i = t; i < N_; i += 256) c += ((keys[i] >> bit) >= (cand >> bit));
    red[t] = c;
    __syncthreads();
    for (int off = 128; off > 0; off >>= 1) { if (t < off) red[t] += red[t + off]; __syncthreads(); }
    if (red[0] >= K_) prefix = cand;
    __syncthreads();
  }
  unsigned T = prefix;
  int c = 0;
  for (int i = t; i < N_; i += 256) c += (keys[i] > T);
  red[t] = c;
  __syncthreads();
  for (int off = 128; off > 0; off >>= 1) { if (t < off) red[t] += red[t + off]; __syncthreads(); }
  int R = K_ - red[0];                          // ties to take, index order
  __syncthreads();
  unsigned kk[8]; int myt = 0;
  for (int j = 0; j < 8; j++) { kk[j] = keys[t * 8 + j]; myt += (kk[j] == T); }
  red[t] = myt;
  __syncthreads();
  for (int off = 1; off < 256; off <<= 1) {
    int x = (t >= off) ? red[t - off] : 0;
    __syncthreads();
    red[t] += x;
    __syncthreads();
  }
  int rank = red[t] - myt;
  for (int j = 0; j < 8; j++) {
    int i = t * 8 + j;
    bool tie = (kk[j] == T);
    bool sel = (kk[j] > T) || (tie && rank < R);
    if (tie) rank++;
    flags[b * N_ + i] = sel ? 1 : 0;
    selw[b * N_ + i] = sel ? tanhf(score[b * N_ + i]) : 0.f;
  }
}

// ---------------- readout partials: sum & max of selected tanh-weighted rows ----------------
__global__ __launch_bounds__(384) void k_readout_part(const unsigned short* __restrict__ cr,
                                                      const float* __restrict__ selw,
                                                      const int* __restrict__ flags,
                                                      float* __restrict__ psum,
                                                      float* __restrict__ pmax) {
  __shared__ int fl[128];
  __shared__ float wv[128];
  int b = blockIdx.x >> 4, ch = blockIdx.x & 15;
  int f = threadIdx.x;
  int n0 = ch * 128;
  if (f < 128) { fl[f] = flags[b * N_ + n0 + f]; wv[f] = selw[b * N_ + n0 + f]; }
  __syncthreads();
  float sum = 0.f, mx = -3.402823466e38f;
  const unsigned short* base = cr + ((size_t)b * N_ + n0) * C_ + f;
  for (int n = 0; n < 128; n++) {
    float v = bf2f(base[(size_t)n * C_]);
    if (fl[n]) { float x = v * wv[n]; sum += x; mx = fmaxf(mx, x); }
  }
  psum[((size_t)b * 16 + ch) * C_ + f] = sum;
  pmax[((size_t)b * 16 + ch) * C_ + f] = mx;
}

__global__ __launch_bounds__(384) void k_readout_red(const float* __restrict__ psum,
                                                     const float* __restrict__ pmax,
                                                     float* __restrict__ g) {
  int b = blockIdx.x, f = threadIdx.x;
  float s = 0.f, m = -3.402823466e38f;
  for (int ch = 0; ch < 16; ch++) {
    s += psum[((size_t)b * 16 + ch) * C_ + f];
    m = fmaxf(m, pmax[((size_t)b * 16 + ch) * C_ + f]);
  }
  g[b * 768 + f] = s * (1.f / K_);
  g[b * 768 + C_ + f] = m;
}

// ---------------- MLP layer 1: h1 = g @ w1 ----------------
__global__ __launch_bounds__(128) void k_mlp1(const float* __restrict__ g,
                                              const float* __restrict__ w1,
                                              float* __restrict__ h1) {
  __shared__ float gr[768];
  int b = blockIdx.x, t = threadIdx.x;
  for (int i = t; i < 768; i += 128) gr[i] = g[b * 768 + i];
  __syncthreads();
  float acc = 0.f;
  for (int k = 0; k < 768; k++) acc += gr[k] * w1[(size_t)k * 128 + t];
  h1[b * 128 + t] = acc;
}

// ---------------- BN + ReLU + mlp_w2 + log_softmax ----------------
__global__ __launch_bounds__(128) void k_mlp2(const float* __restrict__ h1,
                                              const float* __restrict__ bn_g,
                                              const float* __restrict__ bn_b,
                                              const float* __restrict__ w2,
                                              float* __restrict__ out) {
  __shared__ float hn[64][128];
  __shared__ float o[64][10];
  int t = threadIdx.x;   // 128
  float mean = 0.f;
  for (int r = 0; r < 64; r++) mean += h1[r * 128 + t];
  mean *= (1.f / 64.f);
  float var = 0.f;
  for (int r = 0; r < 64; r++) { float d = h1[r * 128 + t] - mean; var += d * d; }
  var *= (1.f / 64.f);
  float sc = bn_g[t] * rsqrtf(var + 1e-5f), sh = bn_b[t];
  for (int r = 0; r < 64; r++) {
    float v = (h1[r * 128 + t] - mean) * sc + sh;
    hn[r][t] = fmaxf(v, 0.f);
  }
  __syncthreads();
  for (int j = 0; j < 5; j++) {
    int idx = t + j * 128;           // 0..639
    int r = idx / 10, c = idx % 10;
    float a = 0.f;
    for (int k = 0; k < 128; k++) a += hn[r][k] * w2[k * 10 + c];
    o[r][c] = a;
  }
  __syncthreads();
  if (t < 64) {
    float mx = -3.402823466e38f;
    for (int c = 0; c < 10; c++) mx = fmaxf(mx, o[t][c]);
    float se = 0.f;
    for (int c = 0; c < 10; c++) se += expf(o[t][c] - mx);
    float l = logf(se);
    for (int c = 0; c < 10; c++) out[t * 10 + c] = o[t][c] - mx - l;
  }
}

extern "C" void kernel_launch(void* const* d_in, const int* in_sizes, int n_in,
                              void* d_out, int out_size, void* d_ws, size_t ws_size,
                              hipStream_t stream) {
  const float* feat = (const float*)d_in[0];
  const int* src = (const int*)d_in[1];
  const int* dst = (const int*)d_in[2];
  const float* W0 = (const float*)d_in[3];  const float* b0 = (const float*)d_in[4];
  const float* W1 = (const float*)d_in[5];  const float* b1 = (const float*)d_in[6];
  const float* W2 = (const float*)d_in[7];  const float* b2 = (const float*)d_in[8];
  const float* Ws = (const float*)d_in[9];  const float* bs = (const float*)d_in[10];
  const float* mw1 = (const float*)d_in[11];
  const float* bng = (const float*)d_in[12];
  const float* bnb = (const float*)d_in[13];
  const float* mw2 = (const float*)d_in[14];
  float* out = (float*)d_out;

  char* p = (char*)d_ws;
  auto alloc = [&](size_t bytes) -> void* {
    void* r = (void*)p;
    p += (bytes + 255) & ~(size_t)255;
    return r;
  };
  int* deg_out = (int*)alloc((size_t)NB_ * 4);
  int* deg_in  = (int*)alloc((size_t)NB_ * 4);
  int* cnt     = (int*)alloc((size_t)NB_ * 4);
  int* row_ptr = (int*)alloc((size_t)B_ * (N_ + 1) * 4);
  float* norm_s = (float*)alloc((size_t)NB_ * 4);
  float* norm_d = (float*)alloc((size_t)NB_ * 4);
  int* csr      = (int*)alloc((size_t)B_ * E_ * 4);
  unsigned short* cr  = (unsigned short*)alloc((size_t)NB_ * C_ * 2);
  unsigned short* agg = (unsigned short*)alloc((size_t)NB_ * F_ * 2);
  float* y     = (float*)alloc((size_t)NB_ * 4);
  float* score = (float*)alloc((size_t)NB_ * 4);
  float* selw  = (float*)alloc((size_t)NB_ * 4);
  int* flags   = (int*)alloc((size_t)NB_ * 4);
  float* psum  = (float*)alloc((size_t)B_ * 16 * C_ * 4);
  float* pmax  = (float*)alloc((size_t)B_ * 16 * C_ * 4);
  float* g     = (float*)alloc((size_t)B_ * 768 * 4);
  float* h1    = (float*)alloc((size_t)B_ * 128 * 4);
  unsigned short* wp0h = (unsigned short*)alloc(16384 * 2);
  unsigned short* wp0l = (unsigned short*)alloc(16384 * 2);
  unsigned short* wp1h = (unsigned short*)alloc(16384 * 2);
  unsigned short* wp1l = (unsigned short*)alloc(16384 * 2);
  unsigned short* wp2h = (unsigned short*)alloc(16384 * 2);
  unsigned short* wp2l = (unsigned short*)alloc(16384 * 2);

  // optional bf16 copy of feat (guarded by workspace size)
  size_t used = (size_t)(p - (char*)d_ws);
  size_t featbf_bytes = (size_t)NB_ * F_ * 2;
  bool use_featbf = (used + featbf_bytes + 256) <= ws_size;
  unsigned short* featbf = use_featbf ? (unsigned short*)alloc(featbf_bytes) : nullptr;

  // zero degree counters + fill counters (contiguous: deg_out, deg_in, cnt)
  hipMemsetAsync(deg_out, 0, (size_t)NB_ * 4 * 3, stream);

  k_degcnt<<<dim3(B_ * E_ / 256), dim3(256), 0, stream>>>(src, dst, deg_out, deg_in);
  k_norms<<<dim3(NB_ / 256), dim3(256), 0, stream>>>(deg_out, deg_in, norm_s, norm_d);
  k_scan<<<dim3(B_), dim3(512), 0, stream>>>(deg_in, row_ptr);
  k_fill<<<dim3(B_ * E_ / 256), dim3(256), 0, stream>>>(src, dst, row_ptr, cnt, csr);

  // weight packs: 32 frags * 64 lanes = 2048 threads = 8 blocks
  k_packW<<<dim3(8), dim3(256), 0, stream>>>(W0, wp0h, wp0l);
  k_packW<<<dim3(8), dim3(256), 0, stream>>>(W1, wp1h, wp1l);
  k_packW<<<dim3(8), dim3(256), 0, stream>>>(W2, wp2h, wp2l);
  if (use_featbf)
    k_f2bf<<<dim3(NB_ * F_ / 8 / 256), dim3(256), 0, stream>>>(feat, featbf);

  // layer 0
  if (use_featbf)
    k_agg<true><<<dim3(NB_ / 8), dim3(256), 0, stream>>>(featbf, F_, 0, row_ptr, csr, norm_s, norm_d, agg);
  else
    k_agg<false><<<dim3(NB_ / 8), dim3(256), 0, stream>>>(feat, F_, 0, row_ptr, csr, norm_s, norm_d, agg);
  k_gemm_mfma<<<dim3(NB_ / 128), dim3(256), 0, stream>>>(agg, wp0h, wp0l, b0, cr, 0);
  // layer 1
  k_agg<true><<<dim3(NB_ / 8), dim3(256), 0, stream>>>(cr, C_, 0, row_ptr, csr, norm_s, norm_d, agg);
  k_gemm_mfma<<<dim3(NB_ / 128), dim3(256), 0, stream>>>(agg, wp1h, wp1l, b1, cr, 128);
  // layer 2
  k_agg<true><<<dim3(NB_ / 8), dim3(256), 0, stream>>>(cr, C_, 128, row_ptr, csr, norm_s, norm_d, agg);
  k_gemm_mfma<<<dim3(NB_ / 128), dim3(256), 0, stream>>>(agg, wp2h, wp2l, b2, cr, 256);

  // SAGPool score
  k_score_y<<<dim3(NB_ / 4), dim3(256), 0, stream>>>(cr, Ws, norm_s, y);
  k_score_agg<<<dim3(NB_ / 256), dim3(256), 0, stream>>>(y, row_ptr, csr, norm_d, bs, score);
  k_topk<<<dim3(B_), dim3(256), 0, stream>>>(score, selw, flags);

  // readout
  k_readout_part<<<dim3(B_ * 16), dim3(384), 0, stream>>>(cr, selw, flags, psum, pmax);
  k_readout_red<<<dim3(B_), dim3(384), 0, stream>>>(psum, pmax, g);

  // MLP
  k_mlp1<<<dim3(B_), dim3(128), 0, stream>>>(g, mw1, h1);
  k_mlp2<<<dim3(1), dim3(128), 0, stream>>>(h1, bng, bnb, mw2, out);
}

// Round 4
// 570.114 us; speedup vs baseline: 1.8594x; 1.4342x over previous
//
#include <hip/hip_runtime.h>
#include <hip/hip_bf16.h>
#include <math.h>

#define B_   64
#define N_   2048
#define E_   32768
#define K_   1024
#define F_   128
#define C_   384
#define NB_  (B_ * N_)

typedef __bf16 bf16x8 __attribute__((ext_vector_type(8)));
typedef float  f32x4  __attribute__((ext_vector_type(4)));

__device__ __forceinline__ float bf2f(unsigned int u) {
  return __uint_as_float(u << 16);   // uses low 16 bits
}
__device__ __forceinline__ unsigned int f2bf(float f) {
  unsigned int x = __float_as_uint(f);
  return (x + 0x7fffu + ((x >> 16) & 1u)) >> 16;   // RNE
}

// ---------------- fused graph prep: one block per graph ----------------
// LDS histograms for deg_out/deg_in (no global atomics), norms, exclusive
// scan of deg_in -> row_ptr, CSR fill with LDS counters.
__global__ __launch_bounds__(1024) void k_prep(const int* __restrict__ src,
                                               const int* __restrict__ dst,
                                               float* __restrict__ norm_s,
                                               float* __restrict__ norm_d,
                                               int* __restrict__ row_ptr,
                                               int* __restrict__ csr) {
  __shared__ int h_out[N_];      // deg_out, later reused as fill counters
  __shared__ int h_in[N_];       // deg_in, later reused as row-start
  __shared__ int part[1024];
  int b = blockIdx.x, t = threadIdx.x;
  h_out[t] = 0; h_out[t + 1024] = 0;
  h_in[t] = 0;  h_in[t + 1024] = 0;
  __syncthreads();
  const int* sp = src + (size_t)b * E_;
  const int* dp = dst + (size_t)b * E_;
  for (int e = t; e < E_; e += 1024) {
    atomicAdd(&h_out[sp[e]], 1);
    atomicAdd(&h_in[dp[e]], 1);
  }
  __syncthreads();
  // norms
  for (int i = t; i < N_; i += 1024) {
    int dv = h_out[i], di = h_in[i];
    norm_s[b * N_ + i] = dv > 0 ? rsqrtf((float)dv) : 0.f;
    norm_d[b * N_ + i] = di > 0 ? rsqrtf((float)di) : 0.f;
  }
  // scan deg_in (2 elems/thread)
  int v0 = h_in[2 * t], v1 = h_in[2 * t + 1], s = v0 + v1;
  part[t] = s;
  __syncthreads();
  for (int off = 1; off < 1024; off <<= 1) {
    int x = (t >= off) ? part[t - off] : 0;
    __syncthreads();
    part[t] += x;
    __syncthreads();
  }
  int base = part[t] - s;        // exclusive start for element 2t
  // reset fill counters (all norms reads of h_out completed before first scan sync)
  h_out[t] = 0; h_out[t + 1024] = 0;
  // write row starts (global + shared)
  row_ptr[b * (N_ + 1) + 2 * t] = base;
  row_ptr[b * (N_ + 1) + 2 * t + 1] = base + v0;
  if (t == 1023) row_ptr[b * (N_ + 1) + N_] = base + v0 + v1;
  __syncthreads();               // h_in reads (v0,v1) all done; safe to overwrite
  h_in[2 * t] = base;
  h_in[2 * t + 1] = base + v0;
  __syncthreads();
  // CSR fill
  int* cg = csr + (size_t)b * E_;
  for (int e = t; e < E_; e += 1024) {
    int d = dp[e], sv = sp[e];
    int pos = h_in[d] + atomicAdd(&h_out[d], 1);
    cg[pos] = sv;
  }
}

// ---------------- feat f32 -> bf16 ----------------
__global__ __launch_bounds__(256) void k_f2bf(const float* __restrict__ in,
                                              unsigned short* __restrict__ out) {
  int i = blockIdx.x * 256 + threadIdx.x;       // NB*128/8 threads, 8 elems each
  const float4* p = (const float4*)(in + (size_t)i * 8);
  float4 v0 = p[0], v1 = p[1];
  uint4 o;
  o.x = f2bf(v0.x) | (f2bf(v0.y) << 16);
  o.y = f2bf(v0.z) | (f2bf(v0.w) << 16);
  o.z = f2bf(v1.x) | (f2bf(v1.y) << 16);
  o.w = f2bf(v1.z) | (f2bf(v1.w) << 16);
  *(uint4*)(out + (size_t)i * 8) = o;
}

// ---------------- aggregate: agg[n][:] = norm_d[n] * sum_{e in in(n)} h[src]*norm_s[src] ----------------
template <bool BF>
__global__ __launch_bounds__(256) void k_agg(const void* __restrict__ hin_,
                                             int stride, int off,
                                             const int* __restrict__ row_ptr,
                                             const int* __restrict__ csr,
                                             const float* __restrict__ norm_s,
                                             const float* __restrict__ norm_d,
                                             unsigned short* __restrict__ agg) {
  int t = threadIdx.x;
  int nl = t >> 5, f4 = t & 31;                  // 8 nodes/block, 32 float4-groups
  int node = blockIdx.x * 8 + nl;
  int b = node >> 11, n = node & (N_ - 1);
  int r0 = row_ptr[b * (N_ + 1) + n], r1 = row_ptr[b * (N_ + 1) + n + 1];
  const int* cs = csr + (size_t)b * E_;
  float a0 = 0.f, a1 = 0.f, a2 = 0.f, a3 = 0.f;
  int e = r0;
  for (; e + 1 < r1; e += 2) {
    int s0 = cs[e], s1 = cs[e + 1];
    float w0 = norm_s[b * N_ + s0];
    float w1 = norm_s[b * N_ + s1];
    if (BF) {
      const unsigned short* p0 = (const unsigned short*)hin_ + (size_t)(b * N_ + s0) * stride + off + f4 * 4;
      const unsigned short* p1 = (const unsigned short*)hin_ + (size_t)(b * N_ + s1) * stride + off + f4 * 4;
      uint2 u0 = *(const uint2*)p0;
      uint2 u1 = *(const uint2*)p1;
      a0 += w0 * bf2f(u0.x); a1 += w0 * bf2f(u0.x >> 16);
      a2 += w0 * bf2f(u0.y); a3 += w0 * bf2f(u0.y >> 16);
      a0 += w1 * bf2f(u1.x); a1 += w1 * bf2f(u1.x >> 16);
      a2 += w1 * bf2f(u1.y); a3 += w1 * bf2f(u1.y >> 16);
    } else {
      const float4 v0 = *(const float4*)((const float*)hin_ + (size_t)(b * N_ + s0) * stride + f4 * 4);
      const float4 v1 = *(const float4*)((const float*)hin_ + (size_t)(b * N_ + s1) * stride + f4 * 4);
      a0 += w0 * v0.x; a1 += w0 * v0.y; a2 += w0 * v0.z; a3 += w0 * v0.w;
      a0 += w1 * v1.x; a1 += w1 * v1.y; a2 += w1 * v1.z; a3 += w1 * v1.w;
    }
  }
  if (e < r1) {
    int s0 = cs[e];
    float w = norm_s[b * N_ + s0];
    if (BF) {
      const unsigned short* p = (const unsigned short*)hin_ + (size_t)(b * N_ + s0) * stride + off + f4 * 4;
      uint2 u = *(const uint2*)p;
      a0 += w * bf2f(u.x); a1 += w * bf2f(u.x >> 16);
      a2 += w * bf2f(u.y); a3 += w * bf2f(u.y >> 16);
    } else {
      const float4 v = *(const float4*)((const float*)hin_ + (size_t)(b * N_ + s0) * stride + f4 * 4);
      a0 += w * v.x; a1 += w * v.y; a2 += w * v.z; a3 += w * v.w;
    }
  }
  float wd = norm_d[node];
  a0 *= wd; a1 *= wd; a2 *= wd; a3 *= wd;
  uint2 o;
  o.x = f2bf(a0) | (f2bf(a1) << 16);
  o.y = f2bf(a2) | (f2bf(a3) << 16);
  *(uint2*)(agg + (size_t)node * F_ + f4 * 4) = o;
}

// ---------------- pack W (f32 [128k][128n]) into MFMA B-fragment layout, bf16 hi/lo ----------------
// fragment (kt, nt): lane holds 8 elems: k = kt*32 + (lane>>4)*8 + j, n = nt*16 + (lane&15)
// 32 fragments x 64 lanes = 2048 threads total.
__global__ __launch_bounds__(256) void k_packW(const float* __restrict__ W,
                                               unsigned short* __restrict__ wp_hi,
                                               unsigned short* __restrict__ wp_lo) {
  int tid = blockIdx.x * 256 + threadIdx.x;     // 2048 = 32 frags * 64 lanes
  int lane = tid & 63, frag = tid >> 6;         // frag = kt*8 + nt
  if (frag >= 32) return;
  int kt = frag >> 3, nt = frag & 7;
  int k0 = kt * 32 + (lane >> 4) * 8;
  int n = nt * 16 + (lane & 15);
  for (int j = 0; j < 8; j++) {
    float w = W[(size_t)(k0 + j) * 128 + n];
    unsigned int hi = f2bf(w);
    float whi = bf2f(hi);
    unsigned int lo = f2bf(w - whi);
    wp_hi[(size_t)tid * 8 + j] = (unsigned short)hi;
    wp_lo[(size_t)tid * 8 + j] = (unsigned short)lo;
  }
}

// ---------------- MFMA GEMM: cr[:, off:off+128] = agg(bf16) @ (Whi+Wlo) + bias ----------------
__global__ __launch_bounds__(256) void k_gemm_mfma(const unsigned short* __restrict__ agg,
                                                   const unsigned short* __restrict__ wp_hi,
                                                   const unsigned short* __restrict__ wp_lo,
                                                   const float* __restrict__ bias,
                                                   unsigned short* __restrict__ cr,
                                                   int out_off) {
  int t = threadIdx.x;
  int wave = t >> 6, lane = t & 63;
  int r0 = blockIdx.x * 128 + wave * 32;        // 32 rows per wave
  int arow = lane & 15, kg = lane >> 4;

  f32x4 acc[2][8];
#pragma unroll
  for (int i = 0; i < 2; i++)
#pragma unroll
    for (int j = 0; j < 8; j++) acc[i][j] = (f32x4){0.f, 0.f, 0.f, 0.f};

#pragma unroll
  for (int kt = 0; kt < 4; ++kt) {
    bf16x8 a0 = *(const bf16x8*)(agg + (size_t)(r0 + arow) * F_ + kt * 32 + kg * 8);
    bf16x8 a1 = *(const bf16x8*)(agg + (size_t)(r0 + 16 + arow) * F_ + kt * 32 + kg * 8);
    const unsigned short* bh = wp_hi + ((size_t)(kt * 8) * 64 + lane) * 8;
    const unsigned short* bl = wp_lo + ((size_t)(kt * 8) * 64 + lane) * 8;
#pragma unroll
    for (int nt = 0; nt < 8; ++nt) {
      bf16x8 bhv = *(const bf16x8*)(bh + (size_t)nt * 64 * 8);
      bf16x8 blv = *(const bf16x8*)(bl + (size_t)nt * 64 * 8);
      acc[0][nt] = __builtin_amdgcn_mfma_f32_16x16x32_bf16(a0, bhv, acc[0][nt], 0, 0, 0);
      acc[0][nt] = __builtin_amdgcn_mfma_f32_16x16x32_bf16(a0, blv, acc[0][nt], 0, 0, 0);
      acc[1][nt] = __builtin_amdgcn_mfma_f32_16x16x32_bf16(a1, bhv, acc[1][nt], 0, 0, 0);
      acc[1][nt] = __builtin_amdgcn_mfma_f32_16x16x32_bf16(a1, blv, acc[1][nt], 0, 0, 0);
    }
  }

  int colt = lane & 15, rbase = (lane >> 4) * 4;
#pragma unroll
  for (int nt = 0; nt < 8; ++nt) {
    float bv = bias[nt * 16 + colt];
#pragma unroll
    for (int rt = 0; rt < 2; ++rt) {
#pragma unroll
      for (int q = 0; q < 4; ++q) {
        int row = r0 + rt * 16 + rbase + q;
        float v = acc[rt][nt][q] + bv;
        cr[(size_t)row * C_ + out_off + nt * 16 + colt] = (unsigned short)f2bf(v);
      }
    }
  }
}

// ---------------- score stage 1: y[n] = (cr[n] . Ws) * norm_s[n] ----------------
__global__ __launch_bounds__(256) void k_score_y(const unsigned short* __restrict__ cr,
                                                 const float* __restrict__ Wsc,
                                                 const float* __restrict__ norm_s,
                                                 float* __restrict__ y) {
  int node = blockIdx.x * 4 + (threadIdx.x >> 6);
  int lane = threadIdx.x & 63;
  const unsigned short* row = cr + (size_t)node * C_;
  float acc = 0.f;
  for (int f = lane; f < C_; f += 64) acc += bf2f(row[f]) * Wsc[f];
  for (int off = 32; off > 0; off >>= 1) acc += __shfl_xor(acc, off);
  if (lane == 0) y[node] = acc * norm_s[node];
}

// ---------------- score stage 2: score[n] = norm_d[n] * sum_in y[src] + bs ----------------
__global__ __launch_bounds__(256) void k_score_agg(const float* __restrict__ y,
                                                   const int* __restrict__ row_ptr,
                                                   const int* __restrict__ csr,
                                                   const float* __restrict__ norm_d,
                                                   const float* __restrict__ bs,
                                                   float* __restrict__ score) {
  int node = blockIdx.x * 256 + threadIdx.x;
  int b = node >> 11, n = node & (N_ - 1);
  int r0 = row_ptr[b * (N_ + 1) + n], r1 = row_ptr[b * (N_ + 1) + n + 1];
  const int* cs = csr + (size_t)b * E_;
  float a = 0.f;
  for (int e = r0; e < r1; ++e) a += y[b * N_ + cs[e]];
  score[node] = norm_d[node] * a + bs[0];
}

// ---------------- top-k selection per graph (K=1024 of 2048) ----------------
__global__ __launch_bounds__(256) void k_topk(const float* __restrict__ score,
                                              float* __restrict__ selw,
                                              int* __restrict__ flags) {
  __shared__ unsigned int keys[N_];
  __shared__ int red[256];
  int b = blockIdx.x, t = threadIdx.x;
  for (int i = t; i < N_; i += 256) {
    unsigned u = __float_as_uint(score[b * N_ + i]);
    keys[i] = (u & 0x80000000u) ? ~u : (u | 0x80000000u);
  }
  __syncthreads();
  unsigned prefix = 0;
  for (int bit = 31; bit >= 0; bit--) {
    unsigned cand = prefix | (1u << bit);
    int c = 0;
    for (int i = t; i < N_; i += 256) c += ((keys[i] >> bit) >= (cand >> bit));
    red[t] = c;
    __syncthreads();
    for (int off = 128; off > 0; off >>= 1) { if (t < off) red[t] += red[t + off]; __syncthreads(); }
    if (red[0] >= K_) prefix = cand;
    __syncthreads();
  }
  unsigned T = prefix;
  int c = 0;
  for (int i = t; i < N_; i += 256) c += (keys[i] > T);
  red[t] = c;
  __syncthreads();
  for (int off = 128; off > 0; off >>= 1) { if (t < off) red[t] += red[t + off]; __syncthreads(); }
  int R = K_ - red[0];                          // ties to take, index order
  __syncthreads();
  unsigned kk[8]; int myt = 0;
  for (int j = 0; j < 8; j++) { kk[j] = keys[t * 8 + j]; myt += (kk[j] == T); }
  red[t] = myt;
  __syncthreads();
  for (int off = 1; off < 256; off <<= 1) {
    int x = (t >= off) ? red[t - off] : 0;
    __syncthreads();
    red[t] += x;
    __syncthreads();
  }
  int rank = red[t] - myt;
  for (int j = 0; j < 8; j++) {
    int i = t * 8 + j;
    bool tie = (kk[j] == T);
    bool sel = (kk[j] > T) || (tie && rank < R);
    if (tie) rank++;
    flags[b * N_ + i] = sel ? 1 : 0;
    selw[b * N_ + i] = sel ? tanhf(score[b * N_ + i]) : 0.f;
  }
}

// ---------------- readout partials: sum & max of selected tanh-weighted rows ----------------
__global__ __launch_bounds__(384) void k_readout_part(const unsigned short* __restrict__ cr,
                                                      const float* __restrict__ selw,
                                                      const int* __restrict__ flags,
                                                      float* __restrict__ psum,
                                                      float* __restrict__ pmax) {
  __shared__ int fl[128];
  __shared__ float wv[128];
  int b = blockIdx.x >> 4, ch = blockIdx.x & 15;
  int f = threadIdx.x;
  int n0 = ch * 128;
  if (f < 128) { fl[f] = flags[b * N_ + n0 + f]; wv[f] = selw[b * N_ + n0 + f]; }
  __syncthreads();
  float sum = 0.f, mx = -3.402823466e38f;
  const unsigned short* base = cr + ((size_t)b * N_ + n0) * C_ + f;
  for (int n = 0; n < 128; n++) {
    float v = bf2f(base[(size_t)n * C_]);
    if (fl[n]) { float x = v * wv[n]; sum += x; mx = fmaxf(mx, x); }
  }
  psum[((size_t)b * 16 + ch) * C_ + f] = sum;
  pmax[((size_t)b * 16 + ch) * C_ + f] = mx;
}

__global__ __launch_bounds__(384) void k_readout_red(const float* __restrict__ psum,
                                                     const float* __restrict__ pmax,
                                                     float* __restrict__ g) {
  int b = blockIdx.x, f = threadIdx.x;
  float s = 0.f, m = -3.402823466e38f;
  for (int ch = 0; ch < 16; ch++) {
    s += psum[((size_t)b * 16 + ch) * C_ + f];
    m = fmaxf(m, pmax[((size_t)b * 16 + ch) * C_ + f]);
  }
  g[b * 768 + f] = s * (1.f / K_);
  g[b * 768 + C_ + f] = m;
}

// ---------------- MLP layer 1: h1 = g @ w1 ----------------
__global__ __launch_bounds__(128) void k_mlp1(const float* __restrict__ g,
                                              const float* __restrict__ w1,
                                              float* __restrict__ h1) {
  __shared__ float gr[768];
  int b = blockIdx.x, t = threadIdx.x;
  for (int i = t; i < 768; i += 128) gr[i] = g[b * 768 + i];
  __syncthreads();
  float acc = 0.f;
  for (int k = 0; k < 768; k++) acc += gr[k] * w1[(size_t)k * 128 + t];
  h1[b * 128 + t] = acc;
}

// ---------------- BN + ReLU + mlp_w2 + log_softmax ----------------
__global__ __launch_bounds__(128) void k_mlp2(const float* __restrict__ h1,
                                              const float* __restrict__ bn_g,
                                              const float* __restrict__ bn_b,
                                              const float* __restrict__ w2,
                                              float* __restrict__ out) {
  __shared__ float hn[64][128];
  __shared__ float o[64][10];
  int t = threadIdx.x;   // 128
  float mean = 0.f;
  for (int r = 0; r < 64; r++) mean += h1[r * 128 + t];
  mean *= (1.f / 64.f);
  float var = 0.f;
  for (int r = 0; r < 64; r++) { float d = h1[r * 128 + t] - mean; var += d * d; }
  var *= (1.f / 64.f);
  float sc = bn_g[t] * rsqrtf(var + 1e-5f), sh = bn_b[t];
  for (int r = 0; r < 64; r++) {
    float v = (h1[r * 128 + t] - mean) * sc + sh;
    hn[r][t] = fmaxf(v, 0.f);
  }
  __syncthreads();
  for (int j = 0; j < 5; j++) {
    int idx = t + j * 128;           // 0..639
    int r = idx / 10, c = idx % 10;
    float a = 0.f;
    for (int k = 0; k < 128; k++) a += hn[r][k] * w2[k * 10 + c];
    o[r][c] = a;
  }
  __syncthreads();
  if (t < 64) {
    float mx = -3.402823466e38f;
    for (int c = 0; c < 10; c++) mx = fmaxf(mx, o[t][c]);
    float se = 0.f;
    for (int c = 0; c < 10; c++) se += expf(o[t][c] - mx);
    float l = logf(se);
    for (int c = 0; c < 10; c++) out[t * 10 + c] = o[t][c] - mx - l;
  }
}

extern "C" void kernel_launch(void* const* d_in, const int* in_sizes, int n_in,
                              void* d_out, int out_size, void* d_ws, size_t ws_size,
                              hipStream_t stream) {
  const float* feat = (const float*)d_in[0];
  const int* src = (const int*)d_in[1];
  const int* dst = (const int*)d_in[2];
  const float* W0 = (const float*)d_in[3];  const float* b0 = (const float*)d_in[4];
  const float* W1 = (const float*)d_in[5];  const float* b1 = (const float*)d_in[6];
  const float* W2 = (const float*)d_in[7];  const float* b2 = (const float*)d_in[8];
  const float* Ws = (const float*)d_in[9];  const float* bs = (const float*)d_in[10];
  const float* mw1 = (const float*)d_in[11];
  const float* bng = (const float*)d_in[12];
  const float* bnb = (const float*)d_in[13];
  const float* mw2 = (const float*)d_in[14];
  float* out = (float*)d_out;

  char* p = (char*)d_ws;
  auto alloc = [&](size_t bytes) -> void* {
    void* r = (void*)p;
    p += (bytes + 255) & ~(size_t)255;
    return r;
  };
  int* row_ptr = (int*)alloc((size_t)B_ * (N_ + 1) * 4);
  float* norm_s = (float*)alloc((size_t)NB_ * 4);
  float* norm_d = (float*)alloc((size_t)NB_ * 4);
  int* csr      = (int*)alloc((size_t)B_ * E_ * 4);
  unsigned short* cr  = (unsigned short*)alloc((size_t)NB_ * C_ * 2);
  unsigned short* agg = (unsigned short*)alloc((size_t)NB_ * F_ * 2);
  float* y     = (float*)alloc((size_t)NB_ * 4);
  float* score = (float*)alloc((size_t)NB_ * 4);
  float* selw  = (float*)alloc((size_t)NB_ * 4);
  int* flags   = (int*)alloc((size_t)NB_ * 4);
  float* psum  = (float*)alloc((size_t)B_ * 16 * C_ * 4);
  float* pmax  = (float*)alloc((size_t)B_ * 16 * C_ * 4);
  float* g     = (float*)alloc((size_t)B_ * 768 * 4);
  float* h1    = (float*)alloc((size_t)B_ * 128 * 4);
  unsigned short* wp0h = (unsigned short*)alloc(16384 * 2);
  unsigned short* wp0l = (unsigned short*)alloc(16384 * 2);
  unsigned short* wp1h = (unsigned short*)alloc(16384 * 2);
  unsigned short* wp1l = (unsigned short*)alloc(16384 * 2);
  unsigned short* wp2h = (unsigned short*)alloc(16384 * 2);
  unsigned short* wp2l = (unsigned short*)alloc(16384 * 2);

  // optional bf16 copy of feat (guarded by workspace size)
  size_t used = (size_t)(p - (char*)d_ws);
  size_t featbf_bytes = (size_t)NB_ * F_ * 2;
  bool use_featbf = (used + featbf_bytes + 256) <= ws_size;
  unsigned short* featbf = use_featbf ? (unsigned short*)alloc(featbf_bytes) : nullptr;

  // fused prep: no global atomics, no memset
  k_prep<<<dim3(B_), dim3(1024), 0, stream>>>(src, dst, norm_s, norm_d, row_ptr, csr);

  // weight packs: 32 frags * 64 lanes = 2048 threads = 8 blocks
  k_packW<<<dim3(8), dim3(256), 0, stream>>>(W0, wp0h, wp0l);
  k_packW<<<dim3(8), dim3(256), 0, stream>>>(W1, wp1h, wp1l);
  k_packW<<<dim3(8), dim3(256), 0, stream>>>(W2, wp2h, wp2l);
  if (use_featbf)
    k_f2bf<<<dim3(NB_ * F_ / 8 / 256), dim3(256), 0, stream>>>(feat, featbf);

  // layer 0
  if (use_featbf)
    k_agg<true><<<dim3(NB_ / 8), dim3(256), 0, stream>>>(featbf, F_, 0, row_ptr, csr, norm_s, norm_d, agg);
  else
    k_agg<false><<<dim3(NB_ / 8), dim3(256), 0, stream>>>(feat, F_, 0, row_ptr, csr, norm_s, norm_d, agg);
  k_gemm_mfma<<<dim3(NB_ / 128), dim3(256), 0, stream>>>(agg, wp0h, wp0l, b0, cr, 0);
  // layer 1
  k_agg<true><<<dim3(NB_ / 8), dim3(256), 0, stream>>>(cr, C_, 0, row_ptr, csr, norm_s, norm_d, agg);
  k_gemm_mfma<<<dim3(NB_ / 128), dim3(256), 0, stream>>>(agg, wp1h, wp1l, b1, cr, 128);
  // layer 2
  k_agg<true><<<dim3(NB_ / 8), dim3(256), 0, stream>>>(cr, C_, 128, row_ptr, csr, norm_s, norm_d, agg);
  k_gemm_mfma<<<dim3(NB_ / 128), dim3(256), 0, stream>>>(agg, wp2h, wp2l, b2, cr, 256);

  // SAGPool score
  k_score_y<<<dim3(NB_ / 4), dim3(256), 0, stream>>>(cr, Ws, norm_s, y);
  k_score_agg<<<dim3(NB_ / 256), dim3(256), 0, stream>>>(y, row_ptr, csr, norm_d, bs, score);
  k_topk<<<dim3(B_), dim3(256), 0, stream>>>(score, selw, flags);

  // readout
  k_readout_part<<<dim3(B_ * 16), dim3(384), 0, stream>>>(cr, selw, flags, psum, pmax);
  k_readout_red<<<dim3(B_), dim3(384), 0, stream>>>(psum, pmax, g);

  // MLP
  k_mlp1<<<dim3(B_), dim3(128), 0, stream>>>(g, mw1, h1);
  k_mlp2<<<dim3(1), dim3(128), 0, stream>>>(h1, bng, bnb, mw2, out);
}

// Round 5
// 505.487 us; speedup vs baseline: 2.0971x; 1.1279x over previous
//
#include <hip/hip_runtime.h>
#include <hip/hip_bf16.h>
#include <math.h>

#define B_   64
#define N_   2048
#define E_   32768
#define K_   1024
#define F_   128
#define C_   384
#define NB_  (B_ * N_)

typedef __bf16 bf16x8 __attribute__((ext_vector_type(8)));
typedef float  f32x4  __attribute__((ext_vector_type(4)));

__device__ __forceinline__ float bf2f(unsigned int u) {
  return __uint_as_float(u << 16);   // uses low 16 bits
}
__device__ __forceinline__ unsigned int f2bf(float f) {
  unsigned int x = __float_as_uint(f);
  return (x + 0x7fffu + ((x >> 16) & 1u)) >> 16;   // RNE
}

// ---------------- fused graph prep: one block per graph ----------------
__global__ __launch_bounds__(1024) void k_prep(const int* __restrict__ src,
                                               const int* __restrict__ dst,
                                               float* __restrict__ norm_s,
                                               float* __restrict__ norm_d,
                                               int* __restrict__ row_ptr,
                                               int* __restrict__ csr) {
  __shared__ int h_out[N_];      // deg_out, later reused as fill counters
  __shared__ int h_in[N_];       // deg_in, later reused as row-start
  __shared__ int part[1024];
  int b = blockIdx.x, t = threadIdx.x;
  h_out[t] = 0; h_out[t + 1024] = 0;
  h_in[t] = 0;  h_in[t + 1024] = 0;
  __syncthreads();
  const int* sp = src + (size_t)b * E_;
  const int* dp = dst + (size_t)b * E_;
  for (int e = t; e < E_; e += 1024) {
    atomicAdd(&h_out[sp[e]], 1);
    atomicAdd(&h_in[dp[e]], 1);
  }
  __syncthreads();
  // norms
  for (int i = t; i < N_; i += 1024) {
    int dv = h_out[i], di = h_in[i];
    norm_s[b * N_ + i] = dv > 0 ? rsqrtf((float)dv) : 0.f;
    norm_d[b * N_ + i] = di > 0 ? rsqrtf((float)di) : 0.f;
  }
  // scan deg_in (2 elems/thread)
  int v0 = h_in[2 * t], v1 = h_in[2 * t + 1], s = v0 + v1;
  part[t] = s;
  __syncthreads();
  for (int off = 1; off < 1024; off <<= 1) {
    int x = (t >= off) ? part[t - off] : 0;
    __syncthreads();
    part[t] += x;
    __syncthreads();
  }
  int base = part[t] - s;        // exclusive start for element 2t
  h_out[t] = 0; h_out[t + 1024] = 0;   // reset fill counters
  row_ptr[b * (N_ + 1) + 2 * t] = base;
  row_ptr[b * (N_ + 1) + 2 * t + 1] = base + v0;
  if (t == 1023) row_ptr[b * (N_ + 1) + N_] = base + v0 + v1;
  __syncthreads();               // all h_in reads (v0,v1) done; safe to overwrite
  h_in[2 * t] = base;
  h_in[2 * t + 1] = base + v0;
  __syncthreads();
  // CSR fill
  int* cg = csr + (size_t)b * E_;
  for (int e = t; e < E_; e += 1024) {
    int d = dp[e], sv = sp[e];
    int pos = h_in[d] + atomicAdd(&h_out[d], 1);
    cg[pos] = sv;
  }
}

// ---------------- feat f32 -> bf16 pre-scaled by norm_s ----------------
__global__ __launch_bounds__(256) void k_f2bf_scaled(const float* __restrict__ in,
                                                     const float* __restrict__ norm_s,
                                                     unsigned short* __restrict__ out) {
  int i = blockIdx.x * 256 + threadIdx.x;       // 8 elems each; node = i>>4
  float ns = norm_s[i >> 4];
  const float4* p = (const float4*)(in + (size_t)i * 8);
  float4 v0 = p[0], v1 = p[1];
  uint4 o;
  o.x = f2bf(v0.x * ns) | (f2bf(v0.y * ns) << 16);
  o.y = f2bf(v0.z * ns) | (f2bf(v0.w * ns) << 16);
  o.z = f2bf(v1.x * ns) | (f2bf(v1.y * ns) << 16);
  o.w = f2bf(v1.z * ns) | (f2bf(v1.w * ns) << 16);
  *(uint4*)(out + (size_t)i * 8) = o;
}

// ---------------- aggregate: agg[n][:] = norm_d[n] * sum_{e in in(n)} hs[src] ----------------
// hs is pre-scaled by norm_s. 16 lanes/node (16B each), 16 nodes/block, 4x unroll.
__global__ __launch_bounds__(256) void k_agg(const unsigned short* __restrict__ hs,
                                             const int* __restrict__ row_ptr,
                                             const int* __restrict__ csr,
                                             const float* __restrict__ norm_d,
                                             unsigned short* __restrict__ agg) {
  int t = threadIdx.x;
  int nl = t >> 4, f8 = t & 15;                  // 16 nodes/block, 16B slices
  int node = blockIdx.x * 16 + nl;
  int b = node >> 11, n = node & (N_ - 1);
  int r0 = row_ptr[b * (N_ + 1) + n], r1 = row_ptr[b * (N_ + 1) + n + 1];
  const int* cs = csr + (size_t)b * E_;
  const unsigned short* hb = hs + ((size_t)b * N_) * F_ + f8 * 8;
  float a0 = 0.f, a1 = 0.f, a2 = 0.f, a3 = 0.f, a4 = 0.f, a5 = 0.f, a6 = 0.f, a7 = 0.f;
#define ACC8(u) { a0 += bf2f(u.x); a1 += bf2f(u.x >> 16); a2 += bf2f(u.y); a3 += bf2f(u.y >> 16); \
                  a4 += bf2f(u.z); a5 += bf2f(u.z >> 16); a6 += bf2f(u.w); a7 += bf2f(u.w >> 16); }
  int e = r0;
  for (; e + 3 < r1; e += 4) {
    int s0 = cs[e], s1 = cs[e + 1], s2 = cs[e + 2], s3 = cs[e + 3];
    uint4 u0 = *(const uint4*)(hb + (size_t)s0 * F_);
    uint4 u1 = *(const uint4*)(hb + (size_t)s1 * F_);
    uint4 u2 = *(const uint4*)(hb + (size_t)s2 * F_);
    uint4 u3 = *(const uint4*)(hb + (size_t)s3 * F_);
    ACC8(u0); ACC8(u1); ACC8(u2); ACC8(u3);
  }
  for (; e < r1; ++e) {
    int s0 = cs[e];
    uint4 u0 = *(const uint4*)(hb + (size_t)s0 * F_);
    ACC8(u0);
  }
#undef ACC8
  float wd = norm_d[node];
  uint4 o;
  o.x = f2bf(a0 * wd) | (f2bf(a1 * wd) << 16);
  o.y = f2bf(a2 * wd) | (f2bf(a3 * wd) << 16);
  o.z = f2bf(a4 * wd) | (f2bf(a5 * wd) << 16);
  o.w = f2bf(a6 * wd) | (f2bf(a7 * wd) << 16);
  *(uint4*)(agg + (size_t)node * F_ + f8 * 8) = o;
}

// ---------------- pack W (f32 [128k][128n]) into MFMA B-fragment layout, bf16 hi/lo ----------------
// fragment (kt, nt): lane holds 8 elems: k = kt*32 + (lane>>4)*8 + j, n = nt*16 + (lane&15)
__global__ __launch_bounds__(256) void k_packW(const float* __restrict__ W,
                                               unsigned short* __restrict__ wp_hi,
                                               unsigned short* __restrict__ wp_lo) {
  int tid = blockIdx.x * 256 + threadIdx.x;     // 2048 = 32 frags * 64 lanes
  int lane = tid & 63, frag = tid >> 6;         // frag = kt*8 + nt
  if (frag >= 32) return;
  int kt = frag >> 3, nt = frag & 7;
  int k0 = kt * 32 + (lane >> 4) * 8;
  int n = nt * 16 + (lane & 15);
  for (int j = 0; j < 8; j++) {
    float w = W[(size_t)(k0 + j) * 128 + n];
    unsigned int hi = f2bf(w);
    float whi = bf2f(hi);
    unsigned int lo = f2bf(w - whi);
    wp_hi[(size_t)tid * 8 + j] = (unsigned short)hi;
    wp_lo[(size_t)tid * 8 + j] = (unsigned short)lo;
  }
}

// ---------------- MFMA GEMM: cr[:, off:off+128] = agg(bf16) @ (Whi+Wlo) + bias ----------------
// If WRITE_HS: also write hs[row][c] = f2bf((acc+bias) * norm_s[row]) for next layer's agg.
template <bool WRITE_HS>
__global__ __launch_bounds__(256) void k_gemm_mfma(const unsigned short* __restrict__ agg,
                                                   const unsigned short* __restrict__ wp_hi,
                                                   const unsigned short* __restrict__ wp_lo,
                                                   const float* __restrict__ bias,
                                                   unsigned short* __restrict__ cr,
                                                   int out_off,
                                                   const float* __restrict__ norm_s,
                                                   unsigned short* __restrict__ hs) {
  int t = threadIdx.x;
  int wave = t >> 6, lane = t & 63;
  int r0 = blockIdx.x * 128 + wave * 32;        // 32 rows per wave
  int arow = lane & 15, kg = lane >> 4;

  f32x4 acc[2][8];
#pragma unroll
  for (int i = 0; i < 2; i++)
#pragma unroll
    for (int j = 0; j < 8; j++) acc[i][j] = (f32x4){0.f, 0.f, 0.f, 0.f};

#pragma unroll
  for (int kt = 0; kt < 4; ++kt) {
    bf16x8 a0 = *(const bf16x8*)(agg + (size_t)(r0 + arow) * F_ + kt * 32 + kg * 8);
    bf16x8 a1 = *(const bf16x8*)(agg + (size_t)(r0 + 16 + arow) * F_ + kt * 32 + kg * 8);
    const unsigned short* bh = wp_hi + ((size_t)(kt * 8) * 64 + lane) * 8;
    const unsigned short* bl = wp_lo + ((size_t)(kt * 8) * 64 + lane) * 8;
#pragma unroll
    for (int nt = 0; nt < 8; ++nt) {
      bf16x8 bhv = *(const bf16x8*)(bh + (size_t)nt * 64 * 8);
      bf16x8 blv = *(const bf16x8*)(bl + (size_t)nt * 64 * 8);
      acc[0][nt] = __builtin_amdgcn_mfma_f32_16x16x32_bf16(a0, bhv, acc[0][nt], 0, 0, 0);
      acc[0][nt] = __builtin_amdgcn_mfma_f32_16x16x32_bf16(a0, blv, acc[0][nt], 0, 0, 0);
      acc[1][nt] = __builtin_amdgcn_mfma_f32_16x16x32_bf16(a1, bhv, acc[1][nt], 0, 0, 0);
      acc[1][nt] = __builtin_amdgcn_mfma_f32_16x16x32_bf16(a1, blv, acc[1][nt], 0, 0, 0);
    }
  }

  int colt = lane & 15, rbase = (lane >> 4) * 4;
  float ns[2][4];
  if (WRITE_HS) {
#pragma unroll
    for (int rt = 0; rt < 2; ++rt)
#pragma unroll
      for (int q = 0; q < 4; ++q) ns[rt][q] = norm_s[r0 + rt * 16 + rbase + q];
  }
#pragma unroll
  for (int nt = 0; nt < 8; ++nt) {
    float bv = bias[nt * 16 + colt];
#pragma unroll
    for (int rt = 0; rt < 2; ++rt) {
#pragma unroll
      for (int q = 0; q < 4; ++q) {
        int row = r0 + rt * 16 + rbase + q;
        float v = acc[rt][nt][q] + bv;
        cr[(size_t)row * C_ + out_off + nt * 16 + colt] = (unsigned short)f2bf(v);
        if (WRITE_HS)
          hs[(size_t)row * F_ + nt * 16 + colt] = (unsigned short)f2bf(v * ns[rt][q]);
      }
    }
  }
}

// ---------------- score stage 1: y[n] = (cr[n] . Ws) * norm_s[n] ----------------
__global__ __launch_bounds__(256) void k_score_y(const unsigned short* __restrict__ cr,
                                                 const float* __restrict__ Wsc,
                                                 const float* __restrict__ norm_s,
                                                 float* __restrict__ y) {
  int node = blockIdx.x * 4 + (threadIdx.x >> 6);
  int lane = threadIdx.x & 63;
  const unsigned short* row = cr + (size_t)node * C_;
  float acc = 0.f;
  for (int f = lane; f < C_; f += 64) acc += bf2f(row[f]) * Wsc[f];
  for (int off = 32; off > 0; off >>= 1) acc += __shfl_xor(acc, off);
  if (lane == 0) y[node] = acc * norm_s[node];
}

// ---------------- score stage 2: score[n] = norm_d[n] * sum_in y[src] + bs ----------------
__global__ __launch_bounds__(256) void k_score_agg(const float* __restrict__ y,
                                                   const int* __restrict__ row_ptr,
                                                   const int* __restrict__ csr,
                                                   const float* __restrict__ norm_d,
                                                   const float* __restrict__ bs,
                                                   float* __restrict__ score) {
  int node = blockIdx.x * 256 + threadIdx.x;
  int b = node >> 11, n = node & (N_ - 1);
  int r0 = row_ptr[b * (N_ + 1) + n], r1 = row_ptr[b * (N_ + 1) + n + 1];
  const int* cs = csr + (size_t)b * E_;
  float a = 0.f;
  for (int e = r0; e < r1; ++e) a += y[b * N_ + cs[e]];
  score[node] = norm_d[node] * a + bs[0];
}

// ---------------- top-k selection per graph (K=1024 of 2048) ----------------
__global__ __launch_bounds__(256) void k_topk(const float* __restrict__ score,
                                              float* __restrict__ selw,
                                              int* __restrict__ flags) {
  __shared__ unsigned int keys[N_];
  __shared__ int red[256];
  int b = blockIdx.x, t = threadIdx.x;
  for (int i = t; i < N_; i += 256) {
    unsigned u = __float_as_uint(score[b * N_ + i]);
    keys[i] = (u & 0x80000000u) ? ~u : (u | 0x80000000u);
  }
  __syncthreads();
  unsigned prefix = 0;
  for (int bit = 31; bit >= 0; bit--) {
    unsigned cand = prefix | (1u << bit);
    int c = 0;
    for (int i = t; i < N_; i += 256) c += ((keys[i] >> bit) >= (cand >> bit));
    red[t] = c;
    __syncthreads();
    for (int off = 128; off > 0; off >>= 1) { if (t < off) red[t] += red[t + off]; __syncthreads(); }
    if (red[0] >= K_) prefix = cand;
    __syncthreads();
  }
  unsigned T = prefix;
  int c = 0;
  for (int i = t; i < N_; i += 256) c += (keys[i] > T);
  red[t] = c;
  __syncthreads();
  for (int off = 128; off > 0; off >>= 1) { if (t < off) red[t] += red[t + off]; __syncthreads(); }
  int R = K_ - red[0];                          // ties to take, index order
  __syncthreads();
  unsigned kk[8]; int myt = 0;
  for (int j = 0; j < 8; j++) { kk[j] = keys[t * 8 + j]; myt += (kk[j] == T); }
  red[t] = myt;
  __syncthreads();
  for (int off = 1; off < 256; off <<= 1) {
    int x = (t >= off) ? red[t - off] : 0;
    __syncthreads();
    red[t] += x;
    __syncthreads();
  }
  int rank = red[t] - myt;
  for (int j = 0; j < 8; j++) {
    int i = t * 8 + j;
    bool tie = (kk[j] == T);
    bool sel = (kk[j] > T) || (tie && rank < R);
    if (tie) rank++;
    flags[b * N_ + i] = sel ? 1 : 0;
    selw[b * N_ + i] = sel ? tanhf(score[b * N_ + i]) : 0.f;
  }
}

// ---------------- readout partials: sum & max of selected tanh-weighted rows ----------------
__global__ __launch_bounds__(384) void k_readout_part(const unsigned short* __restrict__ cr,
                                                      const float* __restrict__ selw,
                                                      const int* __restrict__ flags,
                                                      float* __restrict__ psum,
                                                      float* __restrict__ pmax) {
  __shared__ int fl[128];
  __shared__ float wv[128];
  int b = blockIdx.x >> 4, ch = blockIdx.x & 15;
  int f = threadIdx.x;
  int n0 = ch * 128;
  if (f < 128) { fl[f] = flags[b * N_ + n0 + f]; wv[f] = selw[b * N_ + n0 + f]; }
  __syncthreads();
  float sum = 0.f, mx = -3.402823466e38f;
  const unsigned short* base = cr + ((size_t)b * N_ + n0) * C_ + f;
  for (int n = 0; n < 128; n++) {
    float v = bf2f(base[(size_t)n * C_]);
    if (fl[n]) { float x = v * wv[n]; sum += x; mx = fmaxf(mx, x); }
  }
  psum[((size_t)b * 16 + ch) * C_ + f] = sum;
  pmax[((size_t)b * 16 + ch) * C_ + f] = mx;
}

__global__ __launch_bounds__(384) void k_readout_red(const float* __restrict__ psum,
                                                     const float* __restrict__ pmax,
                                                     float* __restrict__ g) {
  int b = blockIdx.x, f = threadIdx.x;
  float s = 0.f, m = -3.402823466e38f;
  for (int ch = 0; ch < 16; ch++) {
    s += psum[((size_t)b * 16 + ch) * C_ + f];
    m = fmaxf(m, pmax[((size_t)b * 16 + ch) * C_ + f]);
  }
  g[b * 768 + f] = s * (1.f / K_);
  g[b * 768 + C_ + f] = m;
}

// ---------------- MLP layer 1: h1 = g @ w1 ----------------
__global__ __launch_bounds__(128) void k_mlp1(const float* __restrict__ g,
                                              const float* __restrict__ w1,
                                              float* __restrict__ h1) {
  __shared__ float gr[768];
  int b = blockIdx.x, t = threadIdx.x;
  for (int i = t; i < 768; i += 128) gr[i] = g[b * 768 + i];
  __syncthreads();
  float acc = 0.f;
  for (int k = 0; k < 768; k++) acc += gr[k] * w1[(size_t)k * 128 + t];
  h1[b * 128 + t] = acc;
}

// ---------------- BN + ReLU + mlp_w2 + log_softmax ----------------
__global__ __launch_bounds__(128) void k_mlp2(const float* __restrict__ h1,
                                              const float* __restrict__ bn_g,
                                              const float* __restrict__ bn_b,
                                              const float* __restrict__ w2,
                                              float* __restrict__ out) {
  __shared__ float hn[64][128];
  __shared__ float o[64][10];
  int t = threadIdx.x;   // 128
  float mean = 0.f;
  for (int r = 0; r < 64; r++) mean += h1[r * 128 + t];
  mean *= (1.f / 64.f);
  float var = 0.f;
  for (int r = 0; r < 64; r++) { float d = h1[r * 128 + t] - mean; var += d * d; }
  var *= (1.f / 64.f);
  float sc = bn_g[t] * rsqrtf(var + 1e-5f), sh = bn_b[t];
  for (int r = 0; r < 64; r++) {
    float v = (h1[r * 128 + t] - mean) * sc + sh;
    hn[r][t] = fmaxf(v, 0.f);
  }
  __syncthreads();
  for (int j = 0; j < 5; j++) {
    int idx = t + j * 128;           // 0..639
    int r = idx / 10, c = idx % 10;
    float a = 0.f;
    for (int k = 0; k < 128; k++) a += hn[r][k] * w2[k * 10 + c];
    o[r][c] = a;
  }
  __syncthreads();
  if (t < 64) {
    float mx = -3.402823466e38f;
    for (int c = 0; c < 10; c++) mx = fmaxf(mx, o[t][c]);
    float se = 0.f;
    for (int c = 0; c < 10; c++) se += expf(o[t][c] - mx);
    float l = logf(se);
    for (int c = 0; c < 10; c++) out[t * 10 + c] = o[t][c] - mx - l;
  }
}

extern "C" void kernel_launch(void* const* d_in, const int* in_sizes, int n_in,
                              void* d_out, int out_size, void* d_ws, size_t ws_size,
                              hipStream_t stream) {
  const float* feat = (const float*)d_in[0];
  const int* src = (const int*)d_in[1];
  const int* dst = (const int*)d_in[2];
  const float* W0 = (const float*)d_in[3];  const float* b0 = (const float*)d_in[4];
  const float* W1 = (const float*)d_in[5];  const float* b1 = (const float*)d_in[6];
  const float* W2 = (const float*)d_in[7];  const float* b2 = (const float*)d_in[8];
  const float* Ws = (const float*)d_in[9];  const float* bs = (const float*)d_in[10];
  const float* mw1 = (const float*)d_in[11];
  const float* bng = (const float*)d_in[12];
  const float* bnb = (const float*)d_in[13];
  const float* mw2 = (const float*)d_in[14];
  float* out = (float*)d_out;

  char* p = (char*)d_ws;
  auto alloc = [&](size_t bytes) -> void* {
    void* r = (void*)p;
    p += (bytes + 255) & ~(size_t)255;
    return r;
  };
  int* row_ptr = (int*)alloc((size_t)B_ * (N_ + 1) * 4);
  float* norm_s = (float*)alloc((size_t)NB_ * 4);
  float* norm_d = (float*)alloc((size_t)NB_ * 4);
  int* csr      = (int*)alloc((size_t)B_ * E_ * 4);
  unsigned short* cr  = (unsigned short*)alloc((size_t)NB_ * C_ * 2);
  unsigned short* agg = (unsigned short*)alloc((size_t)NB_ * F_ * 2);   // A buffer
  unsigned short* hsb = (unsigned short*)alloc((size_t)NB_ * F_ * 2);   // H buffer
  float* y     = (float*)alloc((size_t)NB_ * 4);
  float* score = (float*)alloc((size_t)NB_ * 4);
  float* selw  = (float*)alloc((size_t)NB_ * 4);
  int* flags   = (int*)alloc((size_t)NB_ * 4);
  float* psum  = (float*)alloc((size_t)B_ * 16 * C_ * 4);
  float* pmax  = (float*)alloc((size_t)B_ * 16 * C_ * 4);
  float* g     = (float*)alloc((size_t)B_ * 768 * 4);
  float* h1    = (float*)alloc((size_t)B_ * 128 * 4);
  unsigned short* wp0h = (unsigned short*)alloc(16384 * 2);
  unsigned short* wp0l = (unsigned short*)alloc(16384 * 2);
  unsigned short* wp1h = (unsigned short*)alloc(16384 * 2);
  unsigned short* wp1l = (unsigned short*)alloc(16384 * 2);
  unsigned short* wp2h = (unsigned short*)alloc(16384 * 2);
  unsigned short* wp2l = (unsigned short*)alloc(16384 * 2);

  // fused prep: no global atomics, no memset
  k_prep<<<dim3(B_), dim3(1024), 0, stream>>>(src, dst, norm_s, norm_d, row_ptr, csr);

  // weight packs: 32 frags * 64 lanes = 2048 threads = 8 blocks
  k_packW<<<dim3(8), dim3(256), 0, stream>>>(W0, wp0h, wp0l);
  k_packW<<<dim3(8), dim3(256), 0, stream>>>(W1, wp1h, wp1l);
  k_packW<<<dim3(8), dim3(256), 0, stream>>>(W2, wp2h, wp2l);

  // hs0 = feat * norm_s (bf16)
  k_f2bf_scaled<<<dim3(NB_ * F_ / 8 / 256), dim3(256), 0, stream>>>(feat, norm_s, hsb);

  // layer 0: agg(hs0) -> A; GEMM -> cr[:,0:128] + hs1 -> H
  k_agg<<<dim3(NB_ / 16), dim3(256), 0, stream>>>(hsb, row_ptr, csr, norm_d, agg);
  k_gemm_mfma<true><<<dim3(NB_ / 128), dim3(256), 0, stream>>>(agg, wp0h, wp0l, b0, cr, 0, norm_s, hsb);
  // layer 1
  k_agg<<<dim3(NB_ / 16), dim3(256), 0, stream>>>(hsb, row_ptr, csr, norm_d, agg);
  k_gemm_mfma<true><<<dim3(NB_ / 128), dim3(256), 0, stream>>>(agg, wp1h, wp1l, b1, cr, 128, norm_s, hsb);
  // layer 2 (no hs needed afterwards)
  k_agg<<<dim3(NB_ / 16), dim3(256), 0, stream>>>(hsb, row_ptr, csr, norm_d, agg);
  k_gemm_mfma<false><<<dim3(NB_ / 128), dim3(256), 0, stream>>>(agg, wp2h, wp2l, b2, cr, 256, norm_s, nullptr);

  // SAGPool score
  k_score_y<<<dim3(NB_ / 4), dim3(256), 0, stream>>>(cr, Ws, norm_s, y);
  k_score_agg<<<dim3(NB_ / 256), dim3(256), 0, stream>>>(y, row_ptr, csr, norm_d, bs, score);
  k_topk<<<dim3(B_), dim3(256), 0, stream>>>(score, selw, flags);

  // readout
  k_readout_part<<<dim3(B_ * 16), dim3(384), 0, stream>>>(cr, selw, flags, psum, pmax);
  k_readout_red<<<dim3(B_), dim3(384), 0, stream>>>(psum, pmax, g);

  // MLP
  k_mlp1<<<dim3(B_), dim3(128), 0, stream>>>(g, mw1, h1);
  k_mlp2<<<dim3(1), dim3(128), 0, stream>>>(h1, bng, bnb, mw2, out);
}